// Round 1
// baseline (1723.621 us; speedup 1.0000x reference)
//
#include <hip/hip_runtime.h>
#include <stdint.h>

#define SEQ    512
#define IN_D   128
#define HID    256
#define OUT_D  64

typedef __attribute__((ext_vector_type(8))) short bf16x8;
typedef __attribute__((ext_vector_type(4))) float f32x4;

__device__ __forceinline__ uint16_t f2bf(float f) {
  union { float f; uint32_t u; } v; v.f = f;
  uint32_t r = v.u + 0x7FFFu + ((v.u >> 16) & 1u);
  return (uint16_t)(r >> 16);
}
__device__ __forceinline__ uint32_t packbf(float a, float b) {
  return (uint32_t)f2bf(a) | ((uint32_t)f2bf(b) << 16);
}

// 256 blocks x 512 threads; block handles 8 batch rows for all 512 steps.
// Wave w owns output cols [32w,32w+32) of the fused K=384 GEMM (B-frags in regs),
// and (waves 0-3) cols [16w,16w+16) of the 64-col output GEMM.
__global__ __launch_bounds__(512, 2) void nlnn_kernel(
    const float* __restrict__ x, const float* __restrict__ h0,
    const float* __restrict__ Win, const float* __restrict__ Wrec,
    const float* __restrict__ Wout, const float* __restrict__ lami,
    const float* __restrict__ lamr, const float* __restrict__ szp,
    const float* __restrict__ araw, float* __restrict__ out) {

  // A-operand staging. Row strides padded (+8 shorts) to break 256B-stride bank aliasing.
  __shared__ __align__(16) short lds_ax[2][16 * 136];  // x_t bf16, double-buffered
  __shared__ __align__(16) short lds_ah[16 * 264];     // h_t bf16 (post-slerp)
  __shared__ __align__(16) float lds_hnew[8 * 256];    // pre-normalize GEMM result fp32

  const int tid = threadIdx.x;
  const int w   = tid >> 6;
  const int l   = tid & 63;
  const int l15 = l & 15;
  const int q   = l >> 4;
  const int blk = blockIdx.x;
  const int row_g = blk * 8 + w;

  // ---- weight B-fragments in registers, lambda folded in ----
  // B-frag layout: lane l holds B[k = 32*kt + 8*(l>>4) + i][col = base + (l&15)]
  bf16x8 wb[12][2];
#pragma unroll
  for (int nt = 0; nt < 2; ++nt) {
    const int col = 32 * w + 16 * nt + l15;
    const float li = lami[col], lr = lamr[col];
#pragma unroll
    for (int kt = 0; kt < 12; ++kt) {
#pragma unroll
      for (int i = 0; i < 8; ++i) {
        const int k = 32 * kt + 8 * q + i;
        const float v = (k < IN_D) ? li * Win[k * HID + col]
                                   : lr * Wrec[(k - IN_D) * HID + col];
        wb[kt][nt][i] = (short)f2bf(v);
      }
    }
  }
  bf16x8 wo[8];
  {
    const float sz = szp[0];  // s_z folded into W_out
    const int col = 16 * (w & 3) + l15;
#pragma unroll
    for (int kt = 0; kt < 8; ++kt)
#pragma unroll
      for (int i = 0; i < 8; ++i) {
        const int k = 32 * kt + 8 * q + i;
        wo[kt][i] = (short)f2bf(sz * Wout[k * OUT_D + col]);
      }
  }

  // alpha = sigmoid(alpha_raw), per-lane cols 4l..4l+3 (same for every wave/row)
  float al[4];
#pragma unroll
  for (int i = 0; i < 4; ++i)
    al[i] = 1.0f / (1.0f + expf(-araw[4 * l + i]));

  // h state: wave w owns row (blk*8+w); lane l holds cols 4l..4l+3 in regs
  float hc[4];
  {
    const f32x4 h4 = *(const f32x4*)&h0[(size_t)row_g * HID + 4 * l];
    hc[0] = h4.x; hc[1] = h4.y; hc[2] = h4.z; hc[3] = h4.w;
    *(uint32_t*)&lds_ah[w * 264 + 4 * l]     = packbf(hc[0], hc[1]);
    *(uint32_t*)&lds_ah[w * 264 + 4 * l + 2] = packbf(hc[2], hc[3]);
  }
  {  // stage x(0)
    const float2 xv = *(const float2*)&x[(size_t)row_g * (SEQ * IN_D) + 2 * l];
    *(uint32_t*)&lds_ax[0][w * 136 + 2 * l] = packbf(xv.x, xv.y);
  }
  __syncthreads();

  for (int t = 0; t < SEQ; ++t) {
    const int p = t & 1;
    const int tn = (t + 1 < SEQ) ? t + 1 : SEQ - 1;
    // prefetch x(t+1) into regs; hidden under the MFMA loop
    const float2 xv = *(const float2*)&x[((size_t)row_g * SEQ + tn) * IN_D + 2 * l];

    // ---- phase A: fused [x|h] @ [li*Win; lr*Wrec], M=16 (rows 0-7 real) ----
    f32x4 acc0 = {0.f, 0.f, 0.f, 0.f};
    f32x4 acc1 = {0.f, 0.f, 0.f, 0.f};
    const short* ax = &lds_ax[p][l15 * 136 + 8 * q];
    const short* ah = &lds_ah[l15 * 264 + 8 * q];
#pragma unroll
    for (int kt = 0; kt < 4; ++kt) {
      bf16x8 a = *(const bf16x8*)(ax + 32 * kt);
      acc0 = __builtin_amdgcn_mfma_f32_16x16x32_bf16(a, wb[kt][0], acc0, 0, 0, 0);
      acc1 = __builtin_amdgcn_mfma_f32_16x16x32_bf16(a, wb[kt][1], acc1, 0, 0, 0);
    }
#pragma unroll
    for (int kt = 0; kt < 8; ++kt) {
      bf16x8 a = *(const bf16x8*)(ah + 32 * kt);
      acc0 = __builtin_amdgcn_mfma_f32_16x16x32_bf16(a, wb[4 + kt][0], acc0, 0, 0, 0);
      acc1 = __builtin_amdgcn_mfma_f32_16x16x32_bf16(a, wb[4 + kt][1], acc1, 0, 0, 0);
    }
    // D-layout: col = lane&15, row = 4*(lane>>4)+reg -> rows 0-7 live in lanes 0-31
    if (l < 32) {
      const int colb = 32 * w + l15;
      const int r0 = 4 * q;
#pragma unroll
      for (int i = 0; i < 4; ++i) {
        lds_hnew[(r0 + i) * HID + colb]      = acc0[i];
        lds_hnew[(r0 + i) * HID + colb + 16] = acc1[i];
      }
    }
    *(uint32_t*)&lds_ax[p ^ 1][w * 136 + 2 * l] = packbf(xv.x, xv.y);
    __syncthreads();

    // ---- phase B: normalize + slerp; wave w = row w, lane l = cols 4l..4l+3 ----
    const f32x4 hn4 = *(const f32x4*)&lds_hnew[w * HID + 4 * l];
    float hn[4] = {hn4.x, hn4.y, hn4.z, hn4.w};
    float ss = hn[0]*hn[0] + hn[1]*hn[1] + hn[2]*hn[2] + hn[3]*hn[3];
    float dt = hc[0]*hn[0] + hc[1]*hn[1] + hc[2]*hn[2] + hc[3]*hn[3];
#pragma unroll
    for (int off = 32; off >= 1; off >>= 1) {
      ss += __shfl_xor(ss, off, 64);
      dt += __shfl_xor(dt, off, 64);
    }
    const float invn = 1.0f / (sqrtf(ss) + 1e-8f);
    float d = dt * invn;                       // dot(h_t, h_new_normalized)
    d = fminf(fmaxf(d, -1.0f), 1.0f);          // clip(+-1e-8) is identity in fp32
    const float th = acosf(d);
    const float st = __sinf(th);
    const bool msk = st > 1e-8f;
    const float den = 1.0f / (st + 1e-8f);
    float res[4]; float ss2 = 0.f;
#pragma unroll
    for (int i = 0; i < 4; ++i) {
      const float hni = hn[i] * invn;
      const float ct = __sinf((1.0f - al[i]) * th) * den;
      const float cn = __sinf(al[i] * th) * den;
      const float r = msk ? (ct * hc[i] + cn * hni) : hni;
      res[i] = r; ss2 += r * r;
    }
#pragma unroll
    for (int off = 32; off >= 1; off >>= 1) ss2 += __shfl_xor(ss2, off, 64);
    const float inv2 = 1.0f / (sqrtf(ss2) + 1e-8f);
#pragma unroll
    for (int i = 0; i < 4; ++i) hc[i] = res[i] * inv2;
    *(uint32_t*)&lds_ah[w * 264 + 4 * l]     = packbf(hc[0], hc[1]);
    *(uint32_t*)&lds_ah[w * 264 + 4 * l + 2] = packbf(hc[2], hc[3]);
    __syncthreads();

    // ---- phase C: out = s_z*(h @ Wout); waves 0-3 only, 4-7 run ahead to A(t+1) ----
    if (w < 4) {
      f32x4 ao = {0.f, 0.f, 0.f, 0.f};
      const short* ah2 = &lds_ah[l15 * 264 + 8 * q];
#pragma unroll
      for (int kt = 0; kt < 8; ++kt) {
        bf16x8 a = *(const bf16x8*)(ah2 + 32 * kt);
        ao = __builtin_amdgcn_mfma_f32_16x16x32_bf16(a, wo[kt], ao, 0, 0, 0);
      }
      if (l < 32) {
        const int col = 16 * w + l15;
        const int r0 = 4 * q;
#pragma unroll
        for (int i = 0; i < 4; ++i)
          out[((size_t)(blk * 8 + r0 + i) * SEQ + t) * OUT_D + col] = ao[i];
      }
    }
  }

  // h_fin, appended after outs
  float* hf = out + (size_t)2048 * SEQ * OUT_D;
  f32x4 hv; hv.x = hc[0]; hv.y = hc[1]; hv.z = hc[2]; hv.w = hc[3];
  *(f32x4*)&hf[(size_t)row_g * HID + 4 * l] = hv;
}

extern "C" void kernel_launch(void* const* d_in, const int* in_sizes, int n_in,
                              void* d_out, int out_size, void* d_ws, size_t ws_size,
                              hipStream_t stream) {
  const float* x    = (const float*)d_in[0];
  const float* h0   = (const float*)d_in[1];
  const float* Win  = (const float*)d_in[2];
  const float* Wrec = (const float*)d_in[3];
  const float* Wout = (const float*)d_in[4];
  const float* li   = (const float*)d_in[5];
  const float* lr   = (const float*)d_in[6];
  const float* sz   = (const float*)d_in[7];
  const float* ar   = (const float*)d_in[8];
  nlnn_kernel<<<256, 512, 0, stream>>>(x, h0, Win, Wrec, Wout, li, lr, sz, ar,
                                       (float*)d_out);
}